// Round 7
// baseline (587.397 us; speedup 1.0000x reference)
//
#include <hip/hip_runtime.h>
#include <hip/hip_bf16.h>
#include <stdint.h>

#define IN_DIM 256

typedef __attribute__((ext_vector_type(8))) short short8;
typedef __attribute__((ext_vector_type(4))) float f32x4;

__device__ __forceinline__ float bf2f(unsigned short u){
  return __uint_as_float(((unsigned int)u) << 16);
}
__device__ __forceinline__ unsigned short f2bf(float f){
  unsigned int u = __float_as_uint(f);
  u = u + 0x7FFFu + ((u >> 16) & 1u);
  return (unsigned short)(u >> 16);
}
__device__ __forceinline__ int rfl(int v){ return __builtin_amdgcn_readfirstlane(v); }

#if __has_builtin(__builtin_amdgcn_cvt_f32_ubyte0)
__device__ __forceinline__ float ub0(uint v){ return __builtin_amdgcn_cvt_f32_ubyte0(v); }
__device__ __forceinline__ float ub1(uint v){ return __builtin_amdgcn_cvt_f32_ubyte1(v); }
__device__ __forceinline__ float ub2(uint v){ return __builtin_amdgcn_cvt_f32_ubyte2(v); }
__device__ __forceinline__ float ub3(uint v){ return __builtin_amdgcn_cvt_f32_ubyte3(v); }
#else
__device__ __forceinline__ float ub0(uint v){ return (float)(v & 0xFF); }
__device__ __forceinline__ float ub1(uint v){ return (float)((v >> 8) & 0xFF); }
__device__ __forceinline__ float ub2(uint v){ return (float)((v >> 16) & 0xFF); }
__device__ __forceinline__ float ub3(uint v){ return (float)(v >> 24); }
#endif

// ---------------- edge dtype detection (int64 vs int32) ----------------
__global__ void k_detect(const void* ei, long long E, int N, int* flag){
  __shared__ int bad;
  if (threadIdx.x == 0) bad = 0;
  __syncthreads();
  const long long* p = (const long long*)ei;
  long long stride = E / 1024; if (stride < 1) stride = 1;
  for (int i = threadIdx.x; i < 1024; i += blockDim.x){
    long long idx = (long long)i * stride;
    if (idx >= E) break;
    long long v = p[idx];
    if (v < 0 || v >= (long long)N) atomicOr(&bad, 1);
  }
  __syncthreads();
  if (threadIdx.x == 0) flag[0] = bad ? 0 : 1;  // 1 = int64 data
}

__device__ __forceinline__ int edge_at(const void* ei, long long i, int f64){
  if (f64) return (int)((const long long*)ei)[i];
  return ((const int*)ei)[i];
}

// ---------------- CSR build ----------------
// hist also compacts the edge list to int32 (dst32/src32) for the XCD-partitioned scatter
__global__ void k_hist(const void* ei, long long E, const int* flag, int* cnt,
                       int* __restrict__ dst32, int* __restrict__ src32){
  long long e = (long long)blockIdx.x * blockDim.x + threadIdx.x;
  if (e < E){
    int f = flag[0];
    int s = edge_at(ei, e, f);
    int d = edge_at(ei, E + e, f);
    src32[e] = s;
    dst32[e] = d;
    atomicAdd(&cnt[d], 1);
  }
}

// scan1 also produces dinv and zeroes fill
__global__ void k_scan1(const int* cnt, int* rs, int* bsum, float* dinv, int* fill, int N){
  __shared__ int sh[1024];
  int i = blockIdx.x * 1024 + threadIdx.x;
  int v = (i < N) ? cnt[i] : 0;
  sh[threadIdx.x] = v;
  __syncthreads();
  for (int o = 1; o < 1024; o <<= 1){
    int x = (threadIdx.x >= o) ? sh[threadIdx.x - o] : 0;
    __syncthreads();
    sh[threadIdx.x] += x;
    __syncthreads();
  }
  if (i < N){
    rs[i] = sh[threadIdx.x] - v;          // exclusive
    dinv[i] = rsqrtf((float)v + 1.0f);
    fill[i] = 0;
  }
  if (threadIdx.x == 1023) bsum[blockIdx.x] = sh[1023];
}

// scan2 also zeroes BN accumulators (4 replicas of 256 each)
__global__ void k_scan2(const int* bsum, int* boff, int nb, int* rs, int N,
                        float* sums, float* sqs){
  __shared__ int sh[128];
  int t = threadIdx.x;
  int v = (t < nb) ? bsum[t] : 0;
  sh[t] = v;
  __syncthreads();
  for (int o = 1; o < 128; o <<= 1){
    int x = (t >= o) ? sh[t - o] : 0;
    __syncthreads();
    sh[t] += x;
    __syncthreads();
  }
  boff[t] = sh[t] - v;
  if (t == 127) rs[N] = sh[127];
  for (int j = t; j < 1024; j += 128){ sums[j] = 0.f; sqs[j] = 0.f; }
}

__global__ void k_scan3(int* rs, const int* boff, int N){
  int i = blockIdx.x * 1024 + threadIdx.x;
  if (i < N) rs[i] += boff[blockIdx.x];
}

// XCD-partitioned scatter: blocks with (blockIdx.x & 7) == g handle only dst in range g.
__global__ __launch_bounds__(256) void k_scatter8(const int* __restrict__ dst32,
    const int* __restrict__ src32, long long E, const int* __restrict__ rs,
    int* __restrict__ fill, int* __restrict__ csrc, int N){
  const int g = blockIdx.x & 7;
  const int bg = blockIdx.x >> 3;          // 0..255 within group
  const int Q = (N + 7) >> 3;
  const int lo = g * Q;
  const int hi = (lo + Q < N) ? lo + Q : N;
  const long long per = (E + 255) / 256;   // edges per block-chunk (256 blocks/group)
  long long e0 = (long long)bg * per;
  long long e1 = e0 + per; if (e1 > E) e1 = E;
  for (long long e = e0 + threadIdx.x; e < e1; e += 256){
    int d = dst32[e];
    if (d >= lo && d < hi){
      int s = src32[e];
      int pos = atomicAdd(&fill[d], 1);
      csrc[rs[d] + pos] = s;
    }
  }
}

// ---------------- weight transpose+convert only (x conversion fused into gemm1q) ------
__global__ void k_prepw(const float* __restrict__ W1, ushort* __restrict__ W1t,
                        const float* __restrict__ W2, ushort* __restrict__ W2t){
  int j = blockIdx.x * 256 + threadIdx.x;
  if (j < 256 * 256){                       // W1t[n*256+k] = W1[k*256+n]
    int n = j >> 8, k = j & 255;
    W1t[j] = f2bf(W1[(size_t)k * 256 + n]);
  } else {
    int j2 = j - 65536;
    if (j2 < 128 * 256){                    // W2t[n*256+k] = W2[k*128+n]
      int n = j2 >> 8, k = j2 & 255;
      W2t[j2] = f2bf(W2[(size_t)k * 128 + n]);
    }
  }
}

// ---------------- GEMM1 + fused row-quant, A staged from fp32 x in-kernel --------------
// BM=128, BN=256 in ONE block: wave w owns rows (w&1)*64..+63, cols (w>>1)*128..+127
// (acc[4][8]). A-tiles are reg-staged from x (float4 load -> f2bf -> ds_write_b64) so the
// separate x->bf16 prep pass and its 150 MB of traffic disappear. B via global_load_lds.
// Row absmax via shfl_xor over the 16-lane col-group + LDS exchange with wave^2.
__global__ __launch_bounds__(256, 2) void k_gemm1q(const float* __restrict__ X,
    const ushort* __restrict__ Bt, unsigned char* __restrict__ q8,
    float* __restrict__ sc1, const float* __restrict__ dinv, int N){
  __shared__ ushort As[128 * 64];
  __shared__ ushort Bs[256 * 64];
  __shared__ float smax[4][64];
  const int tid = threadIdx.x;
  const int wave = tid >> 6, lane = tid & 63;
  const long long row0 = (long long)blockIdx.x * 128;
  const int lr = lane >> 3, lc = lane & 7;
  const int sr = lane >> 4, scq = lane & 15;          // A-stage: 4 rows x 16 col-quads
  const int mrow = ((wave & 1) << 6) + (lane & 15);
  const int ncb = ((wave >> 1) << 7) + (lane & 15);   // this wave's col base + in-frag col

  f32x4 acc[4][8];
  #pragma unroll
  for (int i = 0; i < 4; ++i)
    #pragma unroll
    for (int j = 0; j < 8; ++j)
      acc[i][j] = (f32x4){0.f, 0.f, 0.f, 0.f};

  const ushort* gB = Bt + (wave * 64 + lr) * 256 + lc * 8;
  ushort* lB = Bs + wave * 4096;

  #pragma unroll
  for (int kt = 0; kt < 4; ++kt){
    // B: async direct-to-LDS
    #pragma unroll
    for (int i = 0; i < 8; ++i)
      __builtin_amdgcn_global_load_lds(
          (const __attribute__((address_space(1))) void*)(gB + kt * 64 + i * 8 * 256),
          (__attribute__((address_space(3))) void*)(lB + i * 512), 16, 0, 0);
    // A: reg-stage fp32 -> bf16 (rows wave*32..+31, cols kt*64..+63)
    #pragma unroll
    for (int p = 0; p < 8; ++p){
      int rl = wave * 32 + p * 4 + sr;
      long long grow = row0 + rl;
      float4 xv = {0.f, 0.f, 0.f, 0.f};
      if (grow < N) xv = *(const float4*)(X + grow * 256 + kt * 64 + scq * 4);
      uint2 wv;
      wv.x = (uint)f2bf(xv.x) | ((uint)f2bf(xv.y) << 16);
      wv.y = (uint)f2bf(xv.z) | ((uint)f2bf(xv.w) << 16);
      *(uint2*)(As + rl * 64 + scq * 4) = wv;
    }
    __syncthreads();
    #pragma unroll
    for (int ks = 0; ks < 2; ++ks){
      const int kb = ks * 32 + ((lane >> 4) << 3);
      short8 af[4], bfv[8];
      #pragma unroll
      for (int i = 0; i < 4; ++i) af[i] = *(const short8*)(As + (mrow + i * 16) * 64 + kb);
      #pragma unroll
      for (int j = 0; j < 8; ++j) bfv[j] = *(const short8*)(Bs + (ncb + j * 16) * 64 + kb);
      #pragma unroll
      for (int i = 0; i < 4; ++i)
        #pragma unroll
        for (int j = 0; j < 8; ++j)
          acc[i][j] = __builtin_amdgcn_mfma_f32_16x16x32_bf16(af[i], bfv[j], acc[i][j], 0, 0, 0);
    }
    __syncthreads();
  }

  const int rbase = ((wave & 1) << 6) + ((lane >> 4) << 2);
  float m[4][4];
  #pragma unroll
  for (int i = 0; i < 4; ++i)
    #pragma unroll
    for (int r = 0; r < 4; ++r){
      long long row = row0 + rbase + i * 16 + r;
      float dv = (row < N) ? dinv[row] : 0.f;
      float mm = 0.f;
      #pragma unroll
      for (int j = 0; j < 8; ++j){
        float v = dv * acc[i][j][r];
        acc[i][j][r] = v;
        mm = fmaxf(mm, fabsf(v));
      }
      #pragma unroll
      for (int o = 8; o >= 1; o >>= 1) mm = fmaxf(mm, __shfl_xor(mm, o, 16));
      m[i][r] = mm;
    }
  if ((lane & 15) == 0){
    #pragma unroll
    for (int i = 0; i < 4; ++i)
      #pragma unroll
      for (int r = 0; r < 4; ++r)
        smax[wave][((lane >> 4) << 2) + i * 16 + r] = m[i][r];
  }
  __syncthreads();
  #pragma unroll
  for (int i = 0; i < 4; ++i)
    #pragma unroll
    for (int r = 0; r < 4; ++r){
      int rh = ((lane >> 4) << 2) + i * 16 + r;
      long long row = row0 + ((wave & 1) << 6) + rh;
      float mm = fmaxf(m[i][r], smax[wave ^ 2][rh]);
      float inv = (mm > 0.f) ? 127.0f / mm : 0.f;
      if (wave < 2 && (lane & 15) == 0 && row < N) sc1[row] = mm * (1.0f / 127.0f);
      #pragma unroll
      for (int j = 0; j < 8; ++j){
        unsigned char b = (unsigned char)(int)(rintf(acc[i][j][r] * inv) + 128.0f);
        q8[(size_t)row * 256 + ncb + j * 16] = b;
      }
    }
}

// ---------------- GEMM2 + fused row-quant: q8[row*128+col] int8(+128), sc2[row] ----------------
__global__ __launch_bounds__(256) void k_gemm2q(const ushort* __restrict__ A,
    const ushort* __restrict__ Bt, unsigned char* __restrict__ q8,
    float* __restrict__ sc2, const float* __restrict__ dinv, int N){
  __shared__ ushort As[128 * 64];
  __shared__ ushort Bs[128 * 64];
  __shared__ float smax[4][64];
  const int tid = threadIdx.x;
  const int wave = tid >> 6, lane = tid & 63;
  const long long row0 = (long long)blockIdx.x * 128;
  const int lr = lane >> 3, lc = lane & 7;
  const int mrow = ((wave & 1) << 6) + (lane & 15);
  const int ncol = ((wave >> 1) << 6) + (lane & 15);

  f32x4 acc[4][4];
  #pragma unroll
  for (int i = 0; i < 4; ++i)
    #pragma unroll
    for (int j = 0; j < 4; ++j)
      acc[i][j] = (f32x4){0.f, 0.f, 0.f, 0.f};

  const ushort* gA = A + (row0 + wave * 32 + lr) * 256 + lc * 8;
  const ushort* gB = Bt + ((long long)(wave * 32 + lr)) * 256 + lc * 8;
  ushort* lA = As + wave * 2048;
  ushort* lB = Bs + wave * 2048;

  #pragma unroll
  for (int kt = 0; kt < 4; ++kt){
    #pragma unroll
    for (int i = 0; i < 4; ++i){
      __builtin_amdgcn_global_load_lds(
          (const __attribute__((address_space(1))) void*)(gA + kt * 64 + i * 8 * 256),
          (__attribute__((address_space(3))) void*)(lA + i * 512), 16, 0, 0);
      __builtin_amdgcn_global_load_lds(
          (const __attribute__((address_space(1))) void*)(gB + kt * 64 + i * 8 * 256),
          (__attribute__((address_space(3))) void*)(lB + i * 512), 16, 0, 0);
    }
    __syncthreads();
    #pragma unroll
    for (int ks = 0; ks < 2; ++ks){
      const int kb = ks * 32 + ((lane >> 4) << 3);
      short8 af[4], bfv[4];
      #pragma unroll
      for (int i = 0; i < 4; ++i) af[i] = *(const short8*)(As + (mrow + i * 16) * 64 + kb);
      #pragma unroll
      for (int j = 0; j < 4; ++j) bfv[j] = *(const short8*)(Bs + (ncol + j * 16) * 64 + kb);
      #pragma unroll
      for (int i = 0; i < 4; ++i)
        #pragma unroll
        for (int j = 0; j < 4; ++j)
          acc[i][j] = __builtin_amdgcn_mfma_f32_16x16x32_bf16(af[i], bfv[j], acc[i][j], 0, 0, 0);
    }
    __syncthreads();
  }

  const int rbase = ((wave & 1) << 6) + ((lane >> 4) << 2);
  const int cb = ((wave >> 1) << 6) + (lane & 15);
  float m[4][4];
  #pragma unroll
  for (int i = 0; i < 4; ++i)
    #pragma unroll
    for (int r = 0; r < 4; ++r){
      long long row = row0 + rbase + i * 16 + r;
      float dv = (row < N) ? dinv[row] : 0.f;
      float mm = 0.f;
      #pragma unroll
      for (int j = 0; j < 4; ++j){
        float v = dv * acc[i][j][r];
        acc[i][j][r] = v;
        mm = fmaxf(mm, fabsf(v));
      }
      #pragma unroll
      for (int o = 8; o >= 1; o >>= 1) mm = fmaxf(mm, __shfl_xor(mm, o, 16));
      m[i][r] = mm;
    }
  if ((lane & 15) == 0){
    #pragma unroll
    for (int i = 0; i < 4; ++i)
      #pragma unroll
      for (int r = 0; r < 4; ++r)
        smax[wave][((lane >> 4) << 2) + i * 16 + r] = m[i][r];
  }
  __syncthreads();
  #pragma unroll
  for (int i = 0; i < 4; ++i)
    #pragma unroll
    for (int r = 0; r < 4; ++r){
      int rh = ((lane >> 4) << 2) + i * 16 + r;
      long long row = row0 + ((wave & 1) << 6) + rh;
      float mm = fmaxf(m[i][r], smax[wave ^ 2][rh]);
      float inv = (mm > 0.f) ? 127.0f / mm : 0.f;
      if (wave < 2 && (lane & 15) == 0 && row < N) sc2[row] = mm * (1.0f / 127.0f);
      #pragma unroll
      for (int j = 0; j < 4; ++j){
        unsigned char b = (unsigned char)(int)(rintf(acc[i][j][r] * inv) + 128.0f);
        q8[(size_t)row * 128 + cb + j * 16] = b;
      }
    }
}

// ---------------- aggregation 1: int8 gather, fused BN stats, bf16 out ----------------
// rfl pins wave-uniform index math to SGPRs; MACs are straight FMA chains (8 fma/channel
// vs 8 mul + 8 add of the tree form) — halves the MAC VALU issue.
__global__ __launch_bounds__(256) void k_agg1(const uint* __restrict__ q, const float* __restrict__ sc,
    const int* __restrict__ rs, const int* __restrict__ csrc, const float* __restrict__ b1,
    ushort* __restrict__ h1, float* __restrict__ sums, float* __restrict__ sqs,
    int N, int nblocks){
  __shared__ float red[4 * 512];
  const int lane = threadIdx.x & 63;
  const int wid = rfl((blockIdx.x * 256 + threadIdx.x) >> 6);
  const int nw = (nblocks * 256) >> 6;
  const float4 bb = ((const float4*)b1)[lane];
  const uint* ql = q + lane;
  float st0 = 0.f, st1 = 0.f, st2 = 0.f, st3 = 0.f;
  float sq0 = 0.f, sq1 = 0.f, sq2 = 0.f, sq3 = 0.f;

  for (int n = wid; n < N; n += nw){
    int e = rfl(rs[n]), end = rfl(rs[n + 1]);
    float dn = rsqrtf((float)(end - e) + 1.0f);
    float scn = sc[n];
    uint v = ql[(uint)n << 6];
    float ssum = scn;
    float a0 = scn * ub0(v), a1 = scn * ub1(v), a2 = scn * ub2(v), a3 = scn * ub3(v);
    // unroll-8: 8 independent row-gathers in flight; src indices in SGPRs
    for (; e + 8 <= end; e += 8){
      int s0 = rfl(csrc[e]),     s1 = rfl(csrc[e + 1]), s2 = rfl(csrc[e + 2]), s3 = rfl(csrc[e + 3]);
      int s4 = rfl(csrc[e + 4]), s5 = rfl(csrc[e + 5]), s6 = rfl(csrc[e + 6]), s7 = rfl(csrc[e + 7]);
      float c0 = sc[s0], c1 = sc[s1], c2 = sc[s2], c3 = sc[s3];
      float c4 = sc[s4], c5 = sc[s5], c6 = sc[s6], c7 = sc[s7];
      uint v0 = ql[(uint)s0 << 6];
      uint v1 = ql[(uint)s1 << 6];
      uint v2 = ql[(uint)s2 << 6];
      uint v3 = ql[(uint)s3 << 6];
      uint v4 = ql[(uint)s4 << 6];
      uint v5 = ql[(uint)s5 << 6];
      uint v6 = ql[(uint)s6 << 6];
      uint v7 = ql[(uint)s7 << 6];
      ssum += ((c0 + c1) + (c2 + c3)) + ((c4 + c5) + (c6 + c7));
      a0 = fmaf(c0, ub0(v0), a0); a0 = fmaf(c1, ub0(v1), a0);
      a0 = fmaf(c2, ub0(v2), a0); a0 = fmaf(c3, ub0(v3), a0);
      a0 = fmaf(c4, ub0(v4), a0); a0 = fmaf(c5, ub0(v5), a0);
      a0 = fmaf(c6, ub0(v6), a0); a0 = fmaf(c7, ub0(v7), a0);
      a1 = fmaf(c0, ub1(v0), a1); a1 = fmaf(c1, ub1(v1), a1);
      a1 = fmaf(c2, ub1(v2), a1); a1 = fmaf(c3, ub1(v3), a1);
      a1 = fmaf(c4, ub1(v4), a1); a1 = fmaf(c5, ub1(v5), a1);
      a1 = fmaf(c6, ub1(v6), a1); a1 = fmaf(c7, ub1(v7), a1);
      a2 = fmaf(c0, ub2(v0), a2); a2 = fmaf(c1, ub2(v1), a2);
      a2 = fmaf(c2, ub2(v2), a2); a2 = fmaf(c3, ub2(v3), a2);
      a2 = fmaf(c4, ub2(v4), a2); a2 = fmaf(c5, ub2(v5), a2);
      a2 = fmaf(c6, ub2(v6), a2); a2 = fmaf(c7, ub2(v7), a2);
      a3 = fmaf(c0, ub3(v0), a3); a3 = fmaf(c1, ub3(v1), a3);
      a3 = fmaf(c2, ub3(v2), a3); a3 = fmaf(c3, ub3(v3), a3);
      a3 = fmaf(c4, ub3(v4), a3); a3 = fmaf(c5, ub3(v5), a3);
      a3 = fmaf(c6, ub3(v6), a3); a3 = fmaf(c7, ub3(v7), a3);
    }
    for (; e + 4 <= end; e += 4){
      int s0 = rfl(csrc[e]), s1 = rfl(csrc[e + 1]), s2 = rfl(csrc[e + 2]), s3 = rfl(csrc[e + 3]);
      float c0 = sc[s0], c1 = sc[s1], c2 = sc[s2], c3 = sc[s3];
      uint v0 = ql[(uint)s0 << 6];
      uint v1 = ql[(uint)s1 << 6];
      uint v2 = ql[(uint)s2 << 6];
      uint v3 = ql[(uint)s3 << 6];
      ssum += (c0 + c1) + (c2 + c3);
      a0 = fmaf(c0, ub0(v0), a0); a0 = fmaf(c1, ub0(v1), a0);
      a0 = fmaf(c2, ub0(v2), a0); a0 = fmaf(c3, ub0(v3), a0);
      a1 = fmaf(c0, ub1(v0), a1); a1 = fmaf(c1, ub1(v1), a1);
      a1 = fmaf(c2, ub1(v2), a1); a1 = fmaf(c3, ub1(v3), a1);
      a2 = fmaf(c0, ub2(v0), a2); a2 = fmaf(c1, ub2(v1), a2);
      a2 = fmaf(c2, ub2(v2), a2); a2 = fmaf(c3, ub2(v3), a2);
      a3 = fmaf(c0, ub3(v0), a3); a3 = fmaf(c1, ub3(v1), a3);
      a3 = fmaf(c2, ub3(v2), a3); a3 = fmaf(c3, ub3(v3), a3);
    }
    for (; e < end; ++e){
      int s = rfl(csrc[e]);
      float c = sc[s];
      uint vv = ql[(uint)s << 6];
      ssum += c;
      a0 = fmaf(c, ub0(vv), a0); a1 = fmaf(c, ub1(vv), a1);
      a2 = fmaf(c, ub2(vv), a2); a3 = fmaf(c, ub3(vv), a3);
    }
    float corr = -128.0f * ssum;
    float h0 = dn * (a0 + corr) + bb.x;
    float h1v = dn * (a1 + corr) + bb.y;
    float h2 = dn * (a2 + corr) + bb.z;
    float h3 = dn * (a3 + corr) + bb.w;
    st0 += h0; st1 += h1v; st2 += h2; st3 += h3;
    sq0 += h0 * h0; sq1 += h1v * h1v; sq2 += h2 * h2; sq3 += h3 * h3;
    ushort4 o;
    o.x = f2bf(h0); o.y = f2bf(h1v); o.z = f2bf(h2); o.w = f2bf(h3);
    ((ushort4*)h1)[(size_t)n * 64 + lane] = o;
  }

  // block-reduce stats then atomics (4-replica targets to spread line contention)
  int wv = threadIdx.x >> 6;
  int f = lane * 4;
  red[wv * 512 + f]     = st0; red[wv * 512 + f + 1] = st1;
  red[wv * 512 + f + 2] = st2; red[wv * 512 + f + 3] = st3;
  __syncthreads();
  float v0s = red[threadIdx.x] + red[512 + threadIdx.x] + red[1024 + threadIdx.x] + red[1536 + threadIdx.x];
  __syncthreads();
  red[wv * 512 + f]     = sq0; red[wv * 512 + f + 1] = sq1;
  red[wv * 512 + f + 2] = sq2; red[wv * 512 + f + 3] = sq3;
  __syncthreads();
  float v0q = red[threadIdx.x] + red[512 + threadIdx.x] + red[1024 + threadIdx.x] + red[1536 + threadIdx.x];
  if (threadIdx.x < 256){
    int rep = ((blockIdx.x & 3) << 8) + threadIdx.x;
    atomicAdd(&sums[rep], v0s);
    atomicAdd(&sqs[rep], v0q);
  }
}

// ---------------- aggregation 2: int8 gather, fp32 out ----------------
__global__ __launch_bounds__(256) void k_agg2(const ushort* __restrict__ q, const float* __restrict__ sc,
    const int* __restrict__ rs, const int* __restrict__ csrc, const float* __restrict__ b2,
    float* __restrict__ out, int N, int nblocks){
  const int lane = threadIdx.x & 63;
  const int wid = rfl((blockIdx.x * 256 + threadIdx.x) >> 6);
  const int nw = (nblocks * 256) >> 6;
  const float2 bb = ((const float2*)b2)[lane];
  const ushort* ql = q + lane;

  for (int n = wid; n < N; n += nw){
    int e = rfl(rs[n]), end = rfl(rs[n + 1]);
    float dn = rsqrtf((float)(end - e) + 1.0f);
    float scn = sc[n];
    uint v = (uint)ql[(uint)n << 6];
    float ssum = scn;
    float a0 = scn * ub0(v), a1 = scn * ub1(v);
    for (; e + 8 <= end; e += 8){
      int s0 = rfl(csrc[e]),     s1 = rfl(csrc[e + 1]), s2 = rfl(csrc[e + 2]), s3 = rfl(csrc[e + 3]);
      int s4 = rfl(csrc[e + 4]), s5 = rfl(csrc[e + 5]), s6 = rfl(csrc[e + 6]), s7 = rfl(csrc[e + 7]);
      float c0 = sc[s0], c1 = sc[s1], c2 = sc[s2], c3 = sc[s3];
      float c4 = sc[s4], c5 = sc[s5], c6 = sc[s6], c7 = sc[s7];
      uint v0 = (uint)ql[(uint)s0 << 6];
      uint v1 = (uint)ql[(uint)s1 << 6];
      uint v2 = (uint)ql[(uint)s2 << 6];
      uint v3 = (uint)ql[(uint)s3 << 6];
      uint v4 = (uint)ql[(uint)s4 << 6];
      uint v5 = (uint)ql[(uint)s5 << 6];
      uint v6 = (uint)ql[(uint)s6 << 6];
      uint v7 = (uint)ql[(uint)s7 << 6];
      ssum += ((c0 + c1) + (c2 + c3)) + ((c4 + c5) + (c6 + c7));
      a0 = fmaf(c0, ub0(v0), a0); a0 = fmaf(c1, ub0(v1), a0);
      a0 = fmaf(c2, ub0(v2), a0); a0 = fmaf(c3, ub0(v3), a0);
      a0 = fmaf(c4, ub0(v4), a0); a0 = fmaf(c5, ub0(v5), a0);
      a0 = fmaf(c6, ub0(v6), a0); a0 = fmaf(c7, ub0(v7), a0);
      a1 = fmaf(c0, ub1(v0), a1); a1 = fmaf(c1, ub1(v1), a1);
      a1 = fmaf(c2, ub1(v2), a1); a1 = fmaf(c3, ub1(v3), a1);
      a1 = fmaf(c4, ub1(v4), a1); a1 = fmaf(c5, ub1(v5), a1);
      a1 = fmaf(c6, ub1(v6), a1); a1 = fmaf(c7, ub1(v7), a1);
    }
    for (; e + 4 <= end; e += 4){
      int s0 = rfl(csrc[e]), s1 = rfl(csrc[e + 1]), s2 = rfl(csrc[e + 2]), s3 = rfl(csrc[e + 3]);
      float c0 = sc[s0], c1 = sc[s1], c2 = sc[s2], c3 = sc[s3];
      uint v0 = (uint)ql[(uint)s0 << 6];
      uint v1 = (uint)ql[(uint)s1 << 6];
      uint v2 = (uint)ql[(uint)s2 << 6];
      uint v3 = (uint)ql[(uint)s3 << 6];
      ssum += (c0 + c1) + (c2 + c3);
      a0 = fmaf(c0, ub0(v0), a0); a0 = fmaf(c1, ub0(v1), a0);
      a0 = fmaf(c2, ub0(v2), a0); a0 = fmaf(c3, ub0(v3), a0);
      a1 = fmaf(c0, ub1(v0), a1); a1 = fmaf(c1, ub1(v1), a1);
      a1 = fmaf(c2, ub1(v2), a1); a1 = fmaf(c3, ub1(v3), a1);
    }
    for (; e < end; ++e){
      int s = rfl(csrc[e]);
      float c = sc[s];
      uint vv = (uint)ql[(uint)s << 6];
      ssum += c;
      a0 = fmaf(c, ub0(vv), a0); a1 = fmaf(c, ub1(vv), a1);
    }
    float corr = -128.0f * ssum;
    float2 r;
    r.x = dn * (a0 + corr) + bb.x;
    r.y = dn * (a1 + corr) + bb.y;
    ((float2*)out)[(size_t)n * 64 + lane] = r;
  }
}

// ---------------- BN finalize + apply + PReLU + bf16 cast ----------------
__global__ void k_prelu(const ushort* __restrict__ h1, const float* __restrict__ sums,
                        const float* __restrict__ sqs, const float* __restrict__ gamma,
                        const float* __restrict__ beta, const float* __restrict__ aP,
                        ushort* __restrict__ P, int N, int NP){
  int idx = blockIdx.x * 256 + threadIdx.x;   // NP*128 uint pairs
  int row = idx >> 7, cp = idx & 127;
  if (row >= NP) return;
  uint o = 0;
  if (row < N){
    int c0 = 2 * cp;
    float inv = 1.0f / (float)N;
    float s0 = sums[c0]     + sums[256 + c0]     + sums[512 + c0]     + sums[768 + c0];
    float s1 = sums[c0 + 1] + sums[256 + c0 + 1] + sums[512 + c0 + 1] + sums[768 + c0 + 1];
    float q0 = sqs[c0]      + sqs[256 + c0]      + sqs[512 + c0]      + sqs[768 + c0];
    float q1 = sqs[c0 + 1]  + sqs[256 + c0 + 1]  + sqs[512 + c0 + 1]  + sqs[768 + c0 + 1];
    float m0 = s0 * inv,     m1 = s1 * inv;
    float v0 = q0 * inv - m0 * m0, v1 = q1 * inv - m1 * m1;
    float sc0 = gamma[c0] * rsqrtf(v0 + 1e-5f);
    float sc1 = gamma[c0 + 1] * rsqrtf(v1 + 1e-5f);
    float sh0 = beta[c0] - m0 * sc0;
    float sh1 = beta[c0 + 1] - m1 * sc1;
    uint v = ((const uint*)h1)[(size_t)row * 128 + cp];
    float aa = aP[0];
    float x0 = bf2f((unsigned short)(v & 0xFFFF)) * sc0 + sh0;
    float x1 = bf2f((unsigned short)(v >> 16)) * sc1 + sh1;
    x0 = x0 > 0.f ? x0 : aa * x0;
    x1 = x1 > 0.f ? x1 : aa * x1;
    o = (uint)f2bf(x0) | ((uint)f2bf(x1) << 16);
  }
  ((uint*)P)[idx] = o;
}

extern "C" void kernel_launch(void* const* d_in, const int* in_sizes, int n_in,
                              void* d_out, int out_size, void* d_ws, size_t ws_size,
                              hipStream_t stream){
  const float* x  = (const float*)d_in[0];
  const void*  ei = d_in[1];
  const float* W1 = (const float*)d_in[2];
  const float* b1 = (const float*)d_in[3];
  const float* W2 = (const float*)d_in[4];
  const float* b2 = (const float*)d_in[5];
  const float* gm = (const float*)d_in[6];
  const float* bt = (const float*)d_in[7];
  const float* aP = (const float*)d_in[8];
  float* out = (float*)d_out;

  const int N = in_sizes[0] / IN_DIM;          // 100000
  const long long E = in_sizes[1] / 2;         // 1600000
  const int NP = ((N + 127) / 128) * 128;      // 100096

  char* w = (char*)d_ws;
  size_t off = 0;
  auto carve = [&](size_t bytes) -> char* {
    char* p = w + off;
    off += (bytes + 255) & ~(size_t)255;
    return p;
  };
  ushort* xb  = (ushort*)carve((size_t)NP * 256 * 2);  // P bf16 (prelu -> gemm2q A)
  ushort* hb  = (ushort*)carve((size_t)NP * 256 * 2);  // dst32/src32 (hist->scatter8); then q8a (gemm1q->agg1)
  ushort* h1b = (ushort*)carve((size_t)NP * 256 * 2);  // h1 bf16 (agg1->prelu); then q8b (gemm2q->agg2)
  ushort* W1t = (ushort*)carve(256 * 256 * 2);
  ushort* W2t = (ushort*)carve(128 * 256 * 2);
  int*   cnt  = (int*)  carve((size_t)N * 4);
  int*   rs   = (int*)  carve((size_t)(N + 1) * 4);
  int*   fill = (int*)  carve((size_t)N * 4);
  int*   csrc = (int*)  carve((size_t)E * 4);
  float* dinv = (float*)carve((size_t)N * 4);
  float* sc1  = (float*)carve((size_t)N * 4);
  float* sc2  = (float*)carve((size_t)N * 4);
  int*   bsum = (int*)  carve(512);
  int*   boff = (int*)  carve(512);
  float* sums = (float*)carve(4096);           // 4 replicas x 256
  float* sqs  = (float*)carve(4096);           // 4 replicas x 256
  int*   flag = (int*)  carve(256);
  // aliased buffers (lifetimes verified stream-ordered):
  int*   dst32 = (int*)hb;      // E*4 = 6.4 MB; hist->scatter8 lifetime
  int*   src32 = ((int*)hb) + E;
  uint*   q8a = (uint*)hb;      // [N*64] dwords = 25.6 MB; written by gemm1q AFTER scatter8 drained dst/src
  ushort* q8b = (ushort*)h1b;   // [NP*64] ushorts = 12.8 MB; h1b dead after prelu reads it

  const int NB1 = (N + 1023) / 1024;
  const int egrid = (int)((E + 255) / 256);
  const int AGG1_BLOCKS = 2048, AGG2_BLOCKS = 2048;

  k_detect<<<1, 256, 0, stream>>>(ei, E, N, flag);
  hipMemsetAsync(cnt, 0, (size_t)N * 4, stream);
  k_prepw<<<384, 256, 0, stream>>>(W1, W1t, W2, W2t);
  k_hist<<<egrid, 256, 0, stream>>>(ei, E, flag, cnt, dst32, src32);
  k_scan1<<<NB1, 1024, 0, stream>>>(cnt, rs, bsum, dinv, fill, N);
  k_scan2<<<1, 128, 0, stream>>>(bsum, boff, NB1, rs, N, sums, sqs);
  k_scan3<<<NB1, 1024, 0, stream>>>(rs, boff, N);
  k_scatter8<<<2048, 256, 0, stream>>>(dst32, src32, E, rs, fill, csrc, N);

  // fused GEMM1 + row-quant: reads x (fp32) directly, writes q8a (hb) + sc1.
  k_gemm1q<<<NP / 128, 256, 0, stream>>>(x, W1t, (unsigned char*)q8a, sc1, dinv, N);
  k_agg1<<<AGG1_BLOCKS, 256, 0, stream>>>(q8a, sc1, rs, csrc, b1, h1b, sums, sqs, N, AGG1_BLOCKS);
  k_prelu<<<(NP * 128 + 255) / 256, 256, 0, stream>>>(h1b, sums, sqs, gm, bt, aP, xb, N, NP);
  // fused GEMM2 + row-quant: writes q8b (aliases h1b, dead after prelu) + sc2; no bf16 C.
  k_gemm2q<<<NP / 128, 256, 0, stream>>>(xb, W2t, (unsigned char*)q8b, sc2, dinv, N);
  k_agg2<<<AGG2_BLOCKS, 256, 0, stream>>>(q8b, sc2, rs, csrc, b2, out, N, AGG2_BLOCKS);
}

// Round 9
// 580.273 us; speedup vs baseline: 1.0123x; 1.0123x over previous
//
#include <hip/hip_runtime.h>
#include <hip/hip_bf16.h>
#include <stdint.h>

#define IN_DIM 256

typedef __attribute__((ext_vector_type(8))) short short8;
typedef __attribute__((ext_vector_type(4))) float f32x4;

__device__ __forceinline__ float bf2f(unsigned short u){
  return __uint_as_float(((unsigned int)u) << 16);
}
__device__ __forceinline__ unsigned short f2bf(float f){
  unsigned int u = __float_as_uint(f);
  u = u + 0x7FFFu + ((u >> 16) & 1u);
  return (unsigned short)(u >> 16);
}
__device__ __forceinline__ int rfl(int v){ return __builtin_amdgcn_readfirstlane(v); }

#if __has_builtin(__builtin_amdgcn_cvt_f32_ubyte0)
__device__ __forceinline__ float ub0(uint v){ return __builtin_amdgcn_cvt_f32_ubyte0(v); }
__device__ __forceinline__ float ub1(uint v){ return __builtin_amdgcn_cvt_f32_ubyte1(v); }
__device__ __forceinline__ float ub2(uint v){ return __builtin_amdgcn_cvt_f32_ubyte2(v); }
__device__ __forceinline__ float ub3(uint v){ return __builtin_amdgcn_cvt_f32_ubyte3(v); }
#else
__device__ __forceinline__ float ub0(uint v){ return (float)(v & 0xFF); }
__device__ __forceinline__ float ub1(uint v){ return (float)((v >> 8) & 0xFF); }
__device__ __forceinline__ float ub2(uint v){ return (float)((v >> 16) & 0xFF); }
__device__ __forceinline__ float ub3(uint v){ return (float)(v >> 24); }
#endif

// ---------------- edge dtype detection (int64 vs int32) ----------------
__global__ void k_detect(const void* ei, long long E, int N, int* flag){
  __shared__ int bad;
  if (threadIdx.x == 0) bad = 0;
  __syncthreads();
  const long long* p = (const long long*)ei;
  long long stride = E / 1024; if (stride < 1) stride = 1;
  for (int i = threadIdx.x; i < 1024; i += blockDim.x){
    long long idx = (long long)i * stride;
    if (idx >= E) break;
    long long v = p[idx];
    if (v < 0 || v >= (long long)N) atomicOr(&bad, 1);
  }
  __syncthreads();
  if (threadIdx.x == 0) flag[0] = bad ? 0 : 1;  // 1 = int64 data
}

__device__ __forceinline__ int edge_at(const void* ei, long long i, int f64){
  if (f64) return (int)((const long long*)ei)[i];
  return ((const int*)ei)[i];
}

// ---------------- CSR build ----------------
// hist also compacts the edge list to int32 (dst32/src32) for the XCD-partitioned scatter
__global__ void k_hist(const void* ei, long long E, const int* flag, int* cnt,
                       int* __restrict__ dst32, int* __restrict__ src32){
  long long e = (long long)blockIdx.x * blockDim.x + threadIdx.x;
  if (e < E){
    int f = flag[0];
    int s = edge_at(ei, e, f);
    int d = edge_at(ei, E + e, f);
    src32[e] = s;
    dst32[e] = d;
    atomicAdd(&cnt[d], 1);
  }
}

// scan1 also produces dinv and zeroes fill
__global__ void k_scan1(const int* cnt, int* rs, int* bsum, float* dinv, int* fill, int N){
  __shared__ int sh[1024];
  int i = blockIdx.x * 1024 + threadIdx.x;
  int v = (i < N) ? cnt[i] : 0;
  sh[threadIdx.x] = v;
  __syncthreads();
  for (int o = 1; o < 1024; o <<= 1){
    int x = (threadIdx.x >= o) ? sh[threadIdx.x - o] : 0;
    __syncthreads();
    sh[threadIdx.x] += x;
    __syncthreads();
  }
  if (i < N){
    rs[i] = sh[threadIdx.x] - v;          // exclusive
    dinv[i] = rsqrtf((float)v + 1.0f);
    fill[i] = 0;
  }
  if (threadIdx.x == 1023) bsum[blockIdx.x] = sh[1023];
}

// scan2 also zeroes BN accumulators (4 replicas of 256 each)
__global__ void k_scan2(const int* bsum, int* boff, int nb, int* rs, int N,
                        float* sums, float* sqs){
  __shared__ int sh[128];
  int t = threadIdx.x;
  int v = (t < nb) ? bsum[t] : 0;
  sh[t] = v;
  __syncthreads();
  for (int o = 1; o < 128; o <<= 1){
    int x = (t >= o) ? sh[t - o] : 0;
    __syncthreads();
    sh[t] += x;
    __syncthreads();
  }
  boff[t] = sh[t] - v;
  if (t == 127) rs[N] = sh[127];
  for (int j = t; j < 1024; j += 128){ sums[j] = 0.f; sqs[j] = 0.f; }
}

__global__ void k_scan3(int* rs, const int* boff, int N){
  int i = blockIdx.x * 1024 + threadIdx.x;
  if (i < N) rs[i] += boff[blockIdx.x];
}

// XCD-partitioned scatter: blocks with (blockIdx.x & 7) == g handle only dst in range g.
__global__ __launch_bounds__(256) void k_scatter8(const int* __restrict__ dst32,
    const int* __restrict__ src32, long long E, const int* __restrict__ rs,
    int* __restrict__ fill, int* __restrict__ csrc, int N){
  const int g = blockIdx.x & 7;
  const int bg = blockIdx.x >> 3;          // 0..255 within group
  const int Q = (N + 7) >> 3;
  const int lo = g * Q;
  const int hi = (lo + Q < N) ? lo + Q : N;
  const long long per = (E + 255) / 256;   // edges per block-chunk (256 blocks/group)
  long long e0 = (long long)bg * per;
  long long e1 = e0 + per; if (e1 > E) e1 = E;
  for (long long e = e0 + threadIdx.x; e < e1; e += 256){
    int d = dst32[e];
    if (d >= lo && d < hi){
      int s = src32[e];
      int pos = atomicAdd(&fill[d], 1);
      csrc[rs[d] + pos] = s;
    }
  }
}

// ---------------- fused conversions: xb=bf16(x), W1t, W2t transposed bf16 ----------------
__global__ void k_prep(const float* __restrict__ x, ushort* __restrict__ xb,
                       const float* __restrict__ W1, ushort* __restrict__ W1t,
                       const float* __restrict__ W2, ushort* __restrict__ W2t,
                       int N, int NP){
  int idx = blockIdx.x * 256 + threadIdx.x;
  int nxq = NP * 64;                        // ushort4 groups in xb
  if (idx < nxq){
    int row = idx >> 6, q = idx & 63;
    ushort4 o = {0, 0, 0, 0};
    if (row < N){
      float4 v = ((const float4*)x)[(size_t)row * 64 + q];
      o.x = f2bf(v.x); o.y = f2bf(v.y); o.z = f2bf(v.z); o.w = f2bf(v.w);
    }
    ((ushort4*)xb)[idx] = o;
  } else {
    int j = idx - nxq;
    if (j < 256 * 256){                     // W1t[n*256+k] = W1[k*256+n]
      int n = j >> 8, k = j & 255;
      W1t[j] = f2bf(W1[(size_t)k * 256 + n]);
    } else {
      j -= 65536;
      if (j < 128 * 256){                   // W2t[n*256+k] = W2[k*128+n]
        int n = j >> 8, k = j & 255;
        W2t[j] = f2bf(W2[(size_t)k * 128 + n]);
      }
    }
  }
}

// ---------------- GEMM1 + fused row-quant: q8[row*256+col] int8(+128), sc1[row] ----------------
// BM=128, BN=256 in ONE block: wave w owns rows (w&1)*64..+63, cols (w>>1)*128..+127
// (acc[4][8]). Full output row lives in-block -> row absmax via shfl_xor over the 16-lane
// col-group + LDS exchange with partner wave (w^2). A/B both via global_load_lds (async,
// deep queue — reg-staging A from fp32 was a 48 µs regression, round 7).
__global__ __launch_bounds__(256, 2) void k_gemm1q(const ushort* __restrict__ A,
    const ushort* __restrict__ Bt, unsigned char* __restrict__ q8,
    float* __restrict__ sc1, const float* __restrict__ dinv, int N){
  __shared__ ushort As[128 * 64];
  __shared__ ushort Bs[256 * 64];
  __shared__ float smax[4][64];
  const int tid = threadIdx.x;
  const int wave = tid >> 6, lane = tid & 63;
  const long long row0 = (long long)blockIdx.x * 128;
  const int lr = lane >> 3, lc = lane & 7;
  const int mrow = ((wave & 1) << 6) + (lane & 15);
  const int ncb = ((wave >> 1) << 7) + (lane & 15);   // this wave's col base + in-frag col

  f32x4 acc[4][8];
  #pragma unroll
  for (int i = 0; i < 4; ++i)
    #pragma unroll
    for (int j = 0; j < 8; ++j)
      acc[i][j] = (f32x4){0.f, 0.f, 0.f, 0.f};

  const ushort* gA = A + (row0 + wave * 32 + lr) * 256 + lc * 8;
  const ushort* gB = Bt + (wave * 64 + lr) * 256 + lc * 8;
  ushort* lA = As + wave * 2048;
  ushort* lB = Bs + wave * 4096;

  #pragma unroll
  for (int kt = 0; kt < 4; ++kt){
    #pragma unroll
    for (int i = 0; i < 4; ++i)
      __builtin_amdgcn_global_load_lds(
          (const __attribute__((address_space(1))) void*)(gA + kt * 64 + i * 8 * 256),
          (__attribute__((address_space(3))) void*)(lA + i * 512), 16, 0, 0);
    #pragma unroll
    for (int i = 0; i < 8; ++i)
      __builtin_amdgcn_global_load_lds(
          (const __attribute__((address_space(1))) void*)(gB + kt * 64 + i * 8 * 256),
          (__attribute__((address_space(3))) void*)(lB + i * 512), 16, 0, 0);
    __syncthreads();
    #pragma unroll
    for (int ks = 0; ks < 2; ++ks){
      const int kb = ks * 32 + ((lane >> 4) << 3);
      short8 af[4], bfv[8];
      #pragma unroll
      for (int i = 0; i < 4; ++i) af[i] = *(const short8*)(As + (mrow + i * 16) * 64 + kb);
      #pragma unroll
      for (int j = 0; j < 8; ++j) bfv[j] = *(const short8*)(Bs + (ncb + j * 16) * 64 + kb);
      #pragma unroll
      for (int i = 0; i < 4; ++i)
        #pragma unroll
        for (int j = 0; j < 8; ++j)
          acc[i][j] = __builtin_amdgcn_mfma_f32_16x16x32_bf16(af[i], bfv[j], acc[i][j], 0, 0, 0);
    }
    __syncthreads();
  }

  const int rbase = ((wave & 1) << 6) + ((lane >> 4) << 2);
  float m[4][4];
  #pragma unroll
  for (int i = 0; i < 4; ++i)
    #pragma unroll
    for (int r = 0; r < 4; ++r){
      long long row = row0 + rbase + i * 16 + r;
      float dv = (row < N) ? dinv[row] : 0.f;
      float mm = 0.f;
      #pragma unroll
      for (int j = 0; j < 8; ++j){
        float v = dv * acc[i][j][r];
        acc[i][j][r] = v;
        mm = fmaxf(mm, fabsf(v));
      }
      #pragma unroll
      for (int o = 8; o >= 1; o >>= 1) mm = fmaxf(mm, __shfl_xor(mm, o, 16));
      m[i][r] = mm;
    }
  if ((lane & 15) == 0){
    #pragma unroll
    for (int i = 0; i < 4; ++i)
      #pragma unroll
      for (int r = 0; r < 4; ++r)
        smax[wave][((lane >> 4) << 2) + i * 16 + r] = m[i][r];
  }
  __syncthreads();
  #pragma unroll
  for (int i = 0; i < 4; ++i)
    #pragma unroll
    for (int r = 0; r < 4; ++r){
      int rh = ((lane >> 4) << 2) + i * 16 + r;
      long long row = row0 + ((wave & 1) << 6) + rh;
      float mm = fmaxf(m[i][r], smax[wave ^ 2][rh]);
      float inv = (mm > 0.f) ? 127.0f / mm : 0.f;
      if (wave < 2 && (lane & 15) == 0 && row < N) sc1[row] = mm * (1.0f / 127.0f);
      #pragma unroll
      for (int j = 0; j < 8; ++j){
        unsigned char b = (unsigned char)(int)(rintf(acc[i][j][r] * inv) + 128.0f);
        q8[(size_t)row * 256 + ncb + j * 16] = b;
      }
    }
}

// ---------------- GEMM2 + fused row-quant: q8[row*128+col] int8(+128), sc2[row] ----------------
__global__ __launch_bounds__(256) void k_gemm2q(const ushort* __restrict__ A,
    const ushort* __restrict__ Bt, unsigned char* __restrict__ q8,
    float* __restrict__ sc2, const float* __restrict__ dinv, int N){
  __shared__ ushort As[128 * 64];
  __shared__ ushort Bs[128 * 64];
  __shared__ float smax[4][64];
  const int tid = threadIdx.x;
  const int wave = tid >> 6, lane = tid & 63;
  const long long row0 = (long long)blockIdx.x * 128;
  const int lr = lane >> 3, lc = lane & 7;
  const int mrow = ((wave & 1) << 6) + (lane & 15);
  const int ncol = ((wave >> 1) << 6) + (lane & 15);

  f32x4 acc[4][4];
  #pragma unroll
  for (int i = 0; i < 4; ++i)
    #pragma unroll
    for (int j = 0; j < 4; ++j)
      acc[i][j] = (f32x4){0.f, 0.f, 0.f, 0.f};

  const ushort* gA = A + (row0 + wave * 32 + lr) * 256 + lc * 8;
  const ushort* gB = Bt + ((long long)(wave * 32 + lr)) * 256 + lc * 8;
  ushort* lA = As + wave * 2048;
  ushort* lB = Bs + wave * 2048;

  #pragma unroll
  for (int kt = 0; kt < 4; ++kt){
    #pragma unroll
    for (int i = 0; i < 4; ++i){
      __builtin_amdgcn_global_load_lds(
          (const __attribute__((address_space(1))) void*)(gA + kt * 64 + i * 8 * 256),
          (__attribute__((address_space(3))) void*)(lA + i * 512), 16, 0, 0);
      __builtin_amdgcn_global_load_lds(
          (const __attribute__((address_space(1))) void*)(gB + kt * 64 + i * 8 * 256),
          (__attribute__((address_space(3))) void*)(lB + i * 512), 16, 0, 0);
    }
    __syncthreads();
    #pragma unroll
    for (int ks = 0; ks < 2; ++ks){
      const int kb = ks * 32 + ((lane >> 4) << 3);
      short8 af[4], bfv[4];
      #pragma unroll
      for (int i = 0; i < 4; ++i) af[i] = *(const short8*)(As + (mrow + i * 16) * 64 + kb);
      #pragma unroll
      for (int j = 0; j < 4; ++j) bfv[j] = *(const short8*)(Bs + (ncol + j * 16) * 64 + kb);
      #pragma unroll
      for (int i = 0; i < 4; ++i)
        #pragma unroll
        for (int j = 0; j < 4; ++j)
          acc[i][j] = __builtin_amdgcn_mfma_f32_16x16x32_bf16(af[i], bfv[j], acc[i][j], 0, 0, 0);
    }
    __syncthreads();
  }

  const int rbase = ((wave & 1) << 6) + ((lane >> 4) << 2);
  const int cb = ((wave >> 1) << 6) + (lane & 15);
  float m[4][4];
  #pragma unroll
  for (int i = 0; i < 4; ++i)
    #pragma unroll
    for (int r = 0; r < 4; ++r){
      long long row = row0 + rbase + i * 16 + r;
      float dv = (row < N) ? dinv[row] : 0.f;
      float mm = 0.f;
      #pragma unroll
      for (int j = 0; j < 4; ++j){
        float v = dv * acc[i][j][r];
        acc[i][j][r] = v;
        mm = fmaxf(mm, fabsf(v));
      }
      #pragma unroll
      for (int o = 8; o >= 1; o >>= 1) mm = fmaxf(mm, __shfl_xor(mm, o, 16));
      m[i][r] = mm;
    }
  if ((lane & 15) == 0){
    #pragma unroll
    for (int i = 0; i < 4; ++i)
      #pragma unroll
      for (int r = 0; r < 4; ++r)
        smax[wave][((lane >> 4) << 2) + i * 16 + r] = m[i][r];
  }
  __syncthreads();
  #pragma unroll
  for (int i = 0; i < 4; ++i)
    #pragma unroll
    for (int r = 0; r < 4; ++r){
      int rh = ((lane >> 4) << 2) + i * 16 + r;
      long long row = row0 + ((wave & 1) << 6) + rh;
      float mm = fmaxf(m[i][r], smax[wave ^ 2][rh]);
      float inv = (mm > 0.f) ? 127.0f / mm : 0.f;
      if (wave < 2 && (lane & 15) == 0 && row < N) sc2[row] = mm * (1.0f / 127.0f);
      #pragma unroll
      for (int j = 0; j < 4; ++j){
        unsigned char b = (unsigned char)(int)(rintf(acc[i][j][r] * inv) + 128.0f);
        q8[(size_t)row * 128 + cb + j * 16] = b;
      }
    }
}

// ---------------- aggregation 1: int8 gather, fused BN stats, bf16 out ----------------
// rfl pins wave-uniform index math to SGPRs; MACs are straight FMA chains.
__global__ __launch_bounds__(256) void k_agg1(const uint* __restrict__ q, const float* __restrict__ sc,
    const int* __restrict__ rs, const int* __restrict__ csrc, const float* __restrict__ b1,
    ushort* __restrict__ h1, float* __restrict__ sums, float* __restrict__ sqs,
    int N, int nblocks){
  __shared__ float red[4 * 512];
  const int lane = threadIdx.x & 63;
  const int wid = rfl((blockIdx.x * 256 + threadIdx.x) >> 6);
  const int nw = (nblocks * 256) >> 6;
  const float4 bb = ((const float4*)b1)[lane];
  const uint* ql = q + lane;
  float st0 = 0.f, st1 = 0.f, st2 = 0.f, st3 = 0.f;
  float sq0 = 0.f, sq1 = 0.f, sq2 = 0.f, sq3 = 0.f;

  for (int n = wid; n < N; n += nw){
    int e = rfl(rs[n]), end = rfl(rs[n + 1]);
    float dn = rsqrtf((float)(end - e) + 1.0f);
    float scn = sc[n];
    uint v = ql[(uint)n << 6];
    float ssum = scn;
    float a0 = scn * ub0(v), a1 = scn * ub1(v), a2 = scn * ub2(v), a3 = scn * ub3(v);
    // unroll-8: 8 independent row-gathers in flight; src indices in SGPRs
    for (; e + 8 <= end; e += 8){
      int s0 = rfl(csrc[e]),     s1 = rfl(csrc[e + 1]), s2 = rfl(csrc[e + 2]), s3 = rfl(csrc[e + 3]);
      int s4 = rfl(csrc[e + 4]), s5 = rfl(csrc[e + 5]), s6 = rfl(csrc[e + 6]), s7 = rfl(csrc[e + 7]);
      float c0 = sc[s0], c1 = sc[s1], c2 = sc[s2], c3 = sc[s3];
      float c4 = sc[s4], c5 = sc[s5], c6 = sc[s6], c7 = sc[s7];
      uint v0 = ql[(uint)s0 << 6];
      uint v1 = ql[(uint)s1 << 6];
      uint v2 = ql[(uint)s2 << 6];
      uint v3 = ql[(uint)s3 << 6];
      uint v4 = ql[(uint)s4 << 6];
      uint v5 = ql[(uint)s5 << 6];
      uint v6 = ql[(uint)s6 << 6];
      uint v7 = ql[(uint)s7 << 6];
      ssum += ((c0 + c1) + (c2 + c3)) + ((c4 + c5) + (c6 + c7));
      a0 = fmaf(c0, ub0(v0), a0); a0 = fmaf(c1, ub0(v1), a0);
      a0 = fmaf(c2, ub0(v2), a0); a0 = fmaf(c3, ub0(v3), a0);
      a0 = fmaf(c4, ub0(v4), a0); a0 = fmaf(c5, ub0(v5), a0);
      a0 = fmaf(c6, ub0(v6), a0); a0 = fmaf(c7, ub0(v7), a0);
      a1 = fmaf(c0, ub1(v0), a1); a1 = fmaf(c1, ub1(v1), a1);
      a1 = fmaf(c2, ub1(v2), a1); a1 = fmaf(c3, ub1(v3), a1);
      a1 = fmaf(c4, ub1(v4), a1); a1 = fmaf(c5, ub1(v5), a1);
      a1 = fmaf(c6, ub1(v6), a1); a1 = fmaf(c7, ub1(v7), a1);
      a2 = fmaf(c0, ub2(v0), a2); a2 = fmaf(c1, ub2(v1), a2);
      a2 = fmaf(c2, ub2(v2), a2); a2 = fmaf(c3, ub2(v3), a2);
      a2 = fmaf(c4, ub2(v4), a2); a2 = fmaf(c5, ub2(v5), a2);
      a2 = fmaf(c6, ub2(v6), a2); a2 = fmaf(c7, ub2(v7), a2);
      a3 = fmaf(c0, ub3(v0), a3); a3 = fmaf(c1, ub3(v1), a3);
      a3 = fmaf(c2, ub3(v2), a3); a3 = fmaf(c3, ub3(v3), a3);
      a3 = fmaf(c4, ub3(v4), a3); a3 = fmaf(c5, ub3(v5), a3);
      a3 = fmaf(c6, ub3(v6), a3); a3 = fmaf(c7, ub3(v7), a3);
    }
    for (; e + 4 <= end; e += 4){
      int s0 = rfl(csrc[e]), s1 = rfl(csrc[e + 1]), s2 = rfl(csrc[e + 2]), s3 = rfl(csrc[e + 3]);
      float c0 = sc[s0], c1 = sc[s1], c2 = sc[s2], c3 = sc[s3];
      uint v0 = ql[(uint)s0 << 6];
      uint v1 = ql[(uint)s1 << 6];
      uint v2 = ql[(uint)s2 << 6];
      uint v3 = ql[(uint)s3 << 6];
      ssum += (c0 + c1) + (c2 + c3);
      a0 = fmaf(c0, ub0(v0), a0); a0 = fmaf(c1, ub0(v1), a0);
      a0 = fmaf(c2, ub0(v2), a0); a0 = fmaf(c3, ub0(v3), a0);
      a1 = fmaf(c0, ub1(v0), a1); a1 = fmaf(c1, ub1(v1), a1);
      a1 = fmaf(c2, ub1(v2), a1); a1 = fmaf(c3, ub1(v3), a1);
      a2 = fmaf(c0, ub2(v0), a2); a2 = fmaf(c1, ub2(v1), a2);
      a2 = fmaf(c2, ub2(v2), a2); a2 = fmaf(c3, ub2(v3), a2);
      a3 = fmaf(c0, ub3(v0), a3); a3 = fmaf(c1, ub3(v1), a3);
      a3 = fmaf(c2, ub3(v2), a3); a3 = fmaf(c3, ub3(v3), a3);
    }
    for (; e < end; ++e){
      int s = rfl(csrc[e]);
      float c = sc[s];
      uint vv = ql[(uint)s << 6];
      ssum += c;
      a0 = fmaf(c, ub0(vv), a0); a1 = fmaf(c, ub1(vv), a1);
      a2 = fmaf(c, ub2(vv), a2); a3 = fmaf(c, ub3(vv), a3);
    }
    float corr = -128.0f * ssum;
    float h0 = dn * (a0 + corr) + bb.x;
    float h1v = dn * (a1 + corr) + bb.y;
    float h2 = dn * (a2 + corr) + bb.z;
    float h3 = dn * (a3 + corr) + bb.w;
    st0 += h0; st1 += h1v; st2 += h2; st3 += h3;
    sq0 += h0 * h0; sq1 += h1v * h1v; sq2 += h2 * h2; sq3 += h3 * h3;
    ushort4 o;
    o.x = f2bf(h0); o.y = f2bf(h1v); o.z = f2bf(h2); o.w = f2bf(h3);
    ((ushort4*)h1)[(size_t)n * 64 + lane] = o;
  }

  // block-reduce stats then atomics (4-replica targets to spread line contention)
  int wv = threadIdx.x >> 6;
  int f = lane * 4;
  red[wv * 512 + f]     = st0; red[wv * 512 + f + 1] = st1;
  red[wv * 512 + f + 2] = st2; red[wv * 512 + f + 3] = st3;
  __syncthreads();
  float v0s = red[threadIdx.x] + red[512 + threadIdx.x] + red[1024 + threadIdx.x] + red[1536 + threadIdx.x];
  __syncthreads();
  red[wv * 512 + f]     = sq0; red[wv * 512 + f + 1] = sq1;
  red[wv * 512 + f + 2] = sq2; red[wv * 512 + f + 3] = sq3;
  __syncthreads();
  float v0q = red[threadIdx.x] + red[512 + threadIdx.x] + red[1024 + threadIdx.x] + red[1536 + threadIdx.x];
  if (threadIdx.x < 256){
    int rep = ((blockIdx.x & 3) << 8) + threadIdx.x;
    atomicAdd(&sums[rep], v0s);
    atomicAdd(&sqs[rep], v0q);
  }
}

// ---------------- aggregation 2: int8 gather, fp32 out ----------------
__global__ __launch_bounds__(256) void k_agg2(const ushort* __restrict__ q, const float* __restrict__ sc,
    const int* __restrict__ rs, const int* __restrict__ csrc, const float* __restrict__ b2,
    float* __restrict__ out, int N, int nblocks){
  const int lane = threadIdx.x & 63;
  const int wid = rfl((blockIdx.x * 256 + threadIdx.x) >> 6);
  const int nw = (nblocks * 256) >> 6;
  const float2 bb = ((const float2*)b2)[lane];
  const ushort* ql = q + lane;

  for (int n = wid; n < N; n += nw){
    int e = rfl(rs[n]), end = rfl(rs[n + 1]);
    float dn = rsqrtf((float)(end - e) + 1.0f);
    float scn = sc[n];
    uint v = (uint)ql[(uint)n << 6];
    float ssum = scn;
    float a0 = scn * ub0(v), a1 = scn * ub1(v);
    for (; e + 8 <= end; e += 8){
      int s0 = rfl(csrc[e]),     s1 = rfl(csrc[e + 1]), s2 = rfl(csrc[e + 2]), s3 = rfl(csrc[e + 3]);
      int s4 = rfl(csrc[e + 4]), s5 = rfl(csrc[e + 5]), s6 = rfl(csrc[e + 6]), s7 = rfl(csrc[e + 7]);
      float c0 = sc[s0], c1 = sc[s1], c2 = sc[s2], c3 = sc[s3];
      float c4 = sc[s4], c5 = sc[s5], c6 = sc[s6], c7 = sc[s7];
      uint v0 = (uint)ql[(uint)s0 << 6];
      uint v1 = (uint)ql[(uint)s1 << 6];
      uint v2 = (uint)ql[(uint)s2 << 6];
      uint v3 = (uint)ql[(uint)s3 << 6];
      uint v4 = (uint)ql[(uint)s4 << 6];
      uint v5 = (uint)ql[(uint)s5 << 6];
      uint v6 = (uint)ql[(uint)s6 << 6];
      uint v7 = (uint)ql[(uint)s7 << 6];
      ssum += ((c0 + c1) + (c2 + c3)) + ((c4 + c5) + (c6 + c7));
      a0 = fmaf(c0, ub0(v0), a0); a0 = fmaf(c1, ub0(v1), a0);
      a0 = fmaf(c2, ub0(v2), a0); a0 = fmaf(c3, ub0(v3), a0);
      a0 = fmaf(c4, ub0(v4), a0); a0 = fmaf(c5, ub0(v5), a0);
      a0 = fmaf(c6, ub0(v6), a0); a0 = fmaf(c7, ub0(v7), a0);
      a1 = fmaf(c0, ub1(v0), a1); a1 = fmaf(c1, ub1(v1), a1);
      a1 = fmaf(c2, ub1(v2), a1); a1 = fmaf(c3, ub1(v3), a1);
      a1 = fmaf(c4, ub1(v4), a1); a1 = fmaf(c5, ub1(v5), a1);
      a1 = fmaf(c6, ub1(v6), a1); a1 = fmaf(c7, ub1(v7), a1);
    }
    for (; e + 4 <= end; e += 4){
      int s0 = rfl(csrc[e]), s1 = rfl(csrc[e + 1]), s2 = rfl(csrc[e + 2]), s3 = rfl(csrc[e + 3]);
      float c0 = sc[s0], c1 = sc[s1], c2 = sc[s2], c3 = sc[s3];
      uint v0 = (uint)ql[(uint)s0 << 6];
      uint v1 = (uint)ql[(uint)s1 << 6];
      uint v2 = (uint)ql[(uint)s2 << 6];
      uint v3 = (uint)ql[(uint)s3 << 6];
      ssum += (c0 + c1) + (c2 + c3);
      a0 = fmaf(c0, ub0(v0), a0); a0 = fmaf(c1, ub0(v1), a0);
      a0 = fmaf(c2, ub0(v2), a0); a0 = fmaf(c3, ub0(v3), a0);
      a1 = fmaf(c0, ub1(v0), a1); a1 = fmaf(c1, ub1(v1), a1);
      a1 = fmaf(c2, ub1(v2), a1); a1 = fmaf(c3, ub1(v3), a1);
    }
    for (; e < end; ++e){
      int s = rfl(csrc[e]);
      float c = sc[s];
      uint vv = (uint)ql[(uint)s << 6];
      ssum += c;
      a0 = fmaf(c, ub0(vv), a0); a1 = fmaf(c, ub1(vv), a1);
    }
    float corr = -128.0f * ssum;
    float2 r;
    r.x = dn * (a0 + corr) + bb.x;
    r.y = dn * (a1 + corr) + bb.y;
    ((float2*)out)[(size_t)n * 64 + lane] = r;
  }
}

// ---------------- BN finalize + apply + PReLU + bf16 cast ----------------
__global__ void k_prelu(const ushort* __restrict__ h1, const float* __restrict__ sums,
                        const float* __restrict__ sqs, const float* __restrict__ gamma,
                        const float* __restrict__ beta, const float* __restrict__ aP,
                        ushort* __restrict__ P, int N, int NP){
  int idx = blockIdx.x * 256 + threadIdx.x;   // NP*128 uint pairs
  int row = idx >> 7, cp = idx & 127;
  if (row >= NP) return;
  uint o = 0;
  if (row < N){
    int c0 = 2 * cp;
    float inv = 1.0f / (float)N;
    float s0 = sums[c0]     + sums[256 + c0]     + sums[512 + c0]     + sums[768 + c0];
    float s1 = sums[c0 + 1] + sums[256 + c0 + 1] + sums[512 + c0 + 1] + sums[768 + c0 + 1];
    float q0 = sqs[c0]      + sqs[256 + c0]      + sqs[512 + c0]      + sqs[768 + c0];
    float q1 = sqs[c0 + 1]  + sqs[256 + c0 + 1]  + sqs[512 + c0 + 1]  + sqs[768 + c0 + 1];
    float m0 = s0 * inv,     m1 = s1 * inv;
    float v0 = q0 * inv - m0 * m0, v1 = q1 * inv - m1 * m1;
    float sc0 = gamma[c0] * rsqrtf(v0 + 1e-5f);
    float sc1 = gamma[c0 + 1] * rsqrtf(v1 + 1e-5f);
    float sh0 = beta[c0] - m0 * sc0;
    float sh1 = beta[c0 + 1] - m1 * sc1;
    uint v = ((const uint*)h1)[(size_t)row * 128 + cp];
    float aa = aP[0];
    float x0 = bf2f((unsigned short)(v & 0xFFFF)) * sc0 + sh0;
    float x1 = bf2f((unsigned short)(v >> 16)) * sc1 + sh1;
    x0 = x0 > 0.f ? x0 : aa * x0;
    x1 = x1 > 0.f ? x1 : aa * x1;
    o = (uint)f2bf(x0) | ((uint)f2bf(x1) << 16);
  }
  ((uint*)P)[idx] = o;
}

extern "C" void kernel_launch(void* const* d_in, const int* in_sizes, int n_in,
                              void* d_out, int out_size, void* d_ws, size_t ws_size,
                              hipStream_t stream){
  const float* x  = (const float*)d_in[0];
  const void*  ei = d_in[1];
  const float* W1 = (const float*)d_in[2];
  const float* b1 = (const float*)d_in[3];
  const float* W2 = (const float*)d_in[4];
  const float* b2 = (const float*)d_in[5];
  const float* gm = (const float*)d_in[6];
  const float* bt = (const float*)d_in[7];
  const float* aP = (const float*)d_in[8];
  float* out = (float*)d_out;

  const int N = in_sizes[0] / IN_DIM;          // 100000
  const long long E = in_sizes[1] / 2;         // 1600000
  const int NP = ((N + 127) / 128) * 128;      // 100096

  char* w = (char*)d_ws;
  size_t off = 0;
  auto carve = [&](size_t bytes) -> char* {
    char* p = w + off;
    off += (bytes + 255) & ~(size_t)255;
    return p;
  };
  ushort* xb  = (ushort*)carve((size_t)NP * 256 * 2);  // x bf16 (prep->gemm1q); reused for P after prelu
  ushort* hb  = (ushort*)carve((size_t)NP * 256 * 2);  // dst32/src32 (hist->scatter8); then q8a (gemm1q->agg1)
  ushort* h1b = (ushort*)carve((size_t)NP * 256 * 2);  // h1 bf16 (agg1->prelu); then q8b (gemm2q->agg2)
  ushort* W1t = (ushort*)carve(256 * 256 * 2);
  ushort* W2t = (ushort*)carve(128 * 256 * 2);
  int*   cnt  = (int*)  carve((size_t)N * 4);
  int*   rs   = (int*)  carve((size_t)(N + 1) * 4);
  int*   fill = (int*)  carve((size_t)N * 4);
  int*   csrc = (int*)  carve((size_t)E * 4);
  float* dinv = (float*)carve((size_t)N * 4);
  float* sc1  = (float*)carve((size_t)N * 4);
  float* sc2  = (float*)carve((size_t)N * 4);
  int*   bsum = (int*)  carve(512);
  int*   boff = (int*)  carve(512);
  float* sums = (float*)carve(4096);           // 4 replicas x 256
  float* sqs  = (float*)carve(4096);           // 4 replicas x 256
  int*   flag = (int*)  carve(256);
  // aliased buffers (lifetimes verified stream-ordered):
  int*   dst32 = (int*)hb;      // E*4 = 6.4 MB; hist->scatter8 lifetime
  int*   src32 = ((int*)hb) + E;
  uint*   q8a = (uint*)hb;      // [N*64] dwords = 25.6 MB; written by gemm1q AFTER scatter8 drained dst/src
  ushort* q8b = (ushort*)h1b;   // [NP*64] ushorts = 12.8 MB; h1b dead after prelu reads it

  const int NB1 = (N + 1023) / 1024;
  const int egrid = (int)((E + 255) / 256);
  const int prep_grid = (NP * 64 + 256 * 256 + 128 * 256 + 255) / 256;
  const int AGG1_BLOCKS = 2048, AGG2_BLOCKS = 2048;

  k_detect<<<1, 256, 0, stream>>>(ei, E, N, flag);
  hipMemsetAsync(cnt, 0, (size_t)N * 4, stream);
  k_prep<<<prep_grid, 256, 0, stream>>>(x, xb, W1, W1t, W2, W2t, N, NP);
  k_hist<<<egrid, 256, 0, stream>>>(ei, E, flag, cnt, dst32, src32);
  k_scan1<<<NB1, 1024, 0, stream>>>(cnt, rs, bsum, dinv, fill, N);
  k_scan2<<<1, 128, 0, stream>>>(bsum, boff, NB1, rs, N, sums, sqs);
  k_scan3<<<NB1, 1024, 0, stream>>>(rs, boff, N);
  k_scatter8<<<2048, 256, 0, stream>>>(dst32, src32, E, rs, fill, csrc, N);

  // fused GEMM1 + row-quant: reads xb (bf16), writes q8a (hb) + sc1; no bf16 C, no k_quant1.
  k_gemm1q<<<NP / 128, 256, 0, stream>>>(xb, W1t, (unsigned char*)q8a, sc1, dinv, N);
  k_agg1<<<AGG1_BLOCKS, 256, 0, stream>>>(q8a, sc1, rs, csrc, b1, h1b, sums, sqs, N, AGG1_BLOCKS);
  k_prelu<<<(NP * 128 + 255) / 256, 256, 0, stream>>>(h1b, sums, sqs, gm, bt, aP, xb, N, NP);
  // fused GEMM2 + row-quant: writes q8b (aliases h1b, dead after prelu) + sc2; no bf16 C.
  k_gemm2q<<<NP / 128, 256, 0, stream>>>(xb, W2t, (unsigned char*)q8b, sc2, dinv, N);
  k_agg2<<<AGG2_BLOCKS, 256, 0, stream>>>(q8b, sc2, rs, csrc, b2, out, N, AGG2_BLOCKS);
}